// Round 22
// baseline (662.952 us; speedup 1.0000x reference)
//
#include <hip/hip_runtime.h>

#define NB 64
#define CB 64
#define TB 300
#define VB 25
#define SB 3
#define KB 9
#define NCNTF 480000.0f  // N*T*V per channel

// ws float offsets (stats block)
#define WS_SUM1 0
#define WS_SQ1  64
#define WS_SC1  128
#define WS_SH1  192
#define WS_SUM2 256
#define WS_SQ2  320
#define WS_SC2  384
#define WS_SH2  448
// ws byte offsets
#define WS_WTP_BYTE 2048              // k3 A-frags (32x32): 36*2*64*8 bf16 = 73728 B
#define WS_AQP_BYTE 75776             // k1 stage1 A-frags (Aq hi/lo): 12*64*8 bf16
#define WS_WDP_BYTE 88064             // k1 stage2 A-frags (Wd hi/lo): 48*64*8 bf16
#define WS_TC_BYTE  262144            // tc bf16 [n][o][t*v]: 61.44 MB
// d_out scratch layout (ushort elements)
#define ZP_ELEMS    30720000          // z' bf16 [n][t][v][c] at d_out[0]
                                      // xT bf16 [n][t][v][c] at d_out[ZP_ELEMS]

typedef __attribute__((ext_vector_type(8))) short short8v;
typedef __attribute__((ext_vector_type(4))) float f32x4;
typedef __attribute__((ext_vector_type(16))) float f32x16;

__device__ __forceinline__ float bf2f(unsigned short u) {
  unsigned int v = ((unsigned int)u) << 16;
  float f; __builtin_memcpy(&f, &v, 4); return f;
}
__device__ __forceinline__ unsigned short f2bf(float f) {
  unsigned int x; __builtin_memcpy(&x, &f, 4);
  x += 0x7fffu + ((x >> 16) & 1u);
  return (unsigned short)(x >> 16);
}

// ---------------- K0: prep (pack Wt 32x32, Aq hi/lo, Wd hi/lo) --------------
__global__ void k0_prep(const float* __restrict__ A, const float* __restrict__ PA,
                        const float* __restrict__ Wd, const float* __restrict__ Wt,
                        float* __restrict__ ws) {
  int gid = blockIdx.x * 256 + threadIdx.x;
  int gs  = gridDim.x * 256;
  for (int i = gid; i < 512; i += gs) ws[i] = 0.f;
  // WtP32[kt][mt][l][j] = bf16(Wt[o=mt*32+(l&31)][i=(kt&3)*16+(l>>5)*8+j][tap=kt>>2])
  unsigned short* wtp = (unsigned short*)((char*)ws + WS_WTP_BYTE);
  for (int idx = gid; idx < 36*2*64*8; idx += gs) {
    int j = idx & 7, li = (idx >> 3) & 63, mt = (idx >> 9) & 1, kt = idx >> 10;
    int o = mt*32 + (li & 31);
    int i = (kt & 3)*16 + (li >> 5)*8 + j;
    int tap = kt >> 2;
    wtp[idx] = f2bf(Wt[(o*64 + i)*9 + tap]);
  }
  // AqP: frag f = s*4 + wt*2 + h; lane l; elem j: A[row=w][k=v] hi/lo split
  unsigned short* aqp = (unsigned short*)((char*)ws + WS_AQP_BYTE);
  for (int idx = gid; idx < 12*64*8; idx += gs) {
    int j = idx & 7, l = (idx >> 3) & 63, fi = idx >> 9;
    int h = fi & 1, wt = (fi >> 1) & 1, s = fi >> 2;
    int v = (l >> 4)*8 + j, w = wt*16 + (l & 15);
    unsigned short out = 0;
    if (v < VB && w < VB) {
      int ai = (s*VB + v)*VB + w;
      float a = A[ai] + PA[ai];
      float q = truncf(a * 1024.f);
      q = fminf(fmaxf(q, -32768.f), 32768.f);
      float aq = q * (1.f/1024.f);
      unsigned short hi = f2bf(aq);
      out = h ? f2bf(aq - bf2f(hi)) : hi;
    }
    aqp[idx] = out;
  }
  // WdP: frag fi = (h*6+kt)*4 + mt; A[row=o][k=s*64+c] hi/lo split
  unsigned short* wdp = (unsigned short*)((char*)ws + WS_WDP_BYTE);
  for (int idx = gid; idx < 48*64*8; idx += gs) {
    int j = idx & 7, l = (idx >> 3) & 63, fi = idx >> 9;
    int mt = fi & 3, q2 = fi >> 2;
    int kt = q2 % 6, h = q2 / 6;
    int k = kt*32 + (l >> 4)*8 + j;
    int s = k >> 6, c = k & 63, o = mt*16 + (l & 15);
    float wv = Wd[(s*64 + o)*64 + c];
    unsigned short hi = f2bf(wv);
    wdp[idx] = h ? f2bf(wv - bf2f(hi)) : hi;
  }
}

// ---------------- K1: MFMA GCN, 26.4KB LDS -> 4 blocks/CU, reg-direct out ---
__global__ __launch_bounds__(512, 4) void k1_gcn(
    const float* __restrict__ x, const float* __restrict__ bd,
    const float* __restrict__ ws, float* __restrict__ wstat,
    unsigned short* __restrict__ zout, unsigned short* __restrict__ xtout)
{
  __shared__ __align__(16) char k1lds[26400];
  unsigned short* xtl = (unsigned short*)k1lds;   // [200tv][66c] bf16 (phase A/B)
  char*  xab = k1lds;                             // xa_s [200][128B] swz (aliases xtl)
  int tid = threadIdx.x;
  int t0 = blockIdx.x * 8;               // 38 blocks, t0 up to 296
  int n  = blockIdx.y;
  int wv = tid >> 6, l = tid & 63, r = l & 15, g = l >> 4;
  int lim = 7500 - t0*25; if (lim > 200) lim = 200;   // valid tv rows

  // stage: x float4 -> xtl transpose (bf16). Unstaged rows (tv>=lim) hold
  // garbage; they only feed output columns tw>=lim which are masked (GEMM
  // columns are independent).
  for (int idx4 = tid; idx4 < 3200; idx4 += 512) {
    int c = idx4 / 50, q = idx4 - c*50;
    int tv0 = q*4;
    if (tv0 + 4 <= lim) {
      float4 xv = *(const float4*)(x + (size_t)(n*64 + c)*7500 + t0*25 + tv0);
      xtl[(tv0+0)*66 + c] = f2bf(xv.x);
      xtl[(tv0+1)*66 + c] = f2bf(xv.y);
      xtl[(tv0+2)*66 + c] = f2bf(xv.z);
      xtl[(tv0+3)*66 + c] = f2bf(xv.w);
    }
  }
  __syncthreads();

  // b1 fragments from xtl (wave wv owns t = wv); v>=25 -> 0
  short8v b1[4];
  #pragma unroll
  for (int ct = 0; ct < 4; ++ct) {
    int c = ct*16 + r;
    #pragma unroll
    for (int j = 0; j < 8; ++j) {
      int v = g*8 + j;
      b1[ct][j] = (v < VB) ? (short)xtl[(wv*25 + v)*66 + c] : (short)0;
    }
  }
  // xT emission (coalesced [tv][c] bf16 store)
  for (int idx = tid; idx < 12800; idx += 512) {
    int tv = idx >> 6, c = idx & 63;
    if (tv < lim)
      xtout[n*480000 + t0*1600 + idx] = xtl[tv*66 + c];
  }
  __syncthreads();   // xtl dead; xab takes over the same memory

  const unsigned short* aqp = (const unsigned short*)((const char*)ws + WS_AQP_BYTE);
  const unsigned short* wdp = (const unsigned short*)((const char*)ws + WS_WDP_BYTE);
  int mt2 = wv & 3, th2 = wv >> 2;
  f32x4 acc2[7];
  #pragma unroll
  for (int i = 0; i < 7; ++i) acc2[i] = (f32x4){0.f,0.f,0.f,0.f};

  for (int s = 0; s < SB; ++s) {
    // ---- stage1(s): xa_s[w][c] for all 8 t (wave wv = t); rows 0..199 ----
    #pragma unroll
    for (int wt = 0; wt < 2; ++wt) {
      short8v a1h = *(const short8v*)(aqp + ((s*4 + wt*2 + 0)*64 + l)*8);
      short8v a1l = *(const short8v*)(aqp + ((s*4 + wt*2 + 1)*64 + l)*8);
      f32x4 acc1[4];
      #pragma unroll
      for (int ct = 0; ct < 4; ++ct) acc1[ct] = (f32x4){0.f,0.f,0.f,0.f};
      #pragma unroll
      for (int ct = 0; ct < 4; ++ct) {
        acc1[ct] = __builtin_amdgcn_mfma_f32_16x16x32_bf16(a1h, b1[ct], acc1[ct], 0,0,0);
        acc1[ct] = __builtin_amdgcn_mfma_f32_16x16x32_bf16(a1l, b1[ct], acc1[ct], 0,0,0);
      }
      #pragma unroll
      for (int ct = 0; ct < 4; ++ct)
        #pragma unroll
        for (int reg = 0; reg < 4; ++reg) {
          int w = wt*16 + g*4 + reg;
          if (w < VB) {
            int row = wv*25 + w, c = ct*16 + r;
            int bir = (c*2) ^ ((row & 7) << 4);
            *(unsigned short*)(xab + row*128 + bir) = f2bf(acc1[ct][reg]);
          }
        }
    }
    __syncthreads();
    // ---- stage2(s): z += Wd[:,s-chunk] @ xa_s (K=64) ----
    #pragma unroll
    for (int ktl = 0; ktl < 2; ++ktl) {
      int kt = s*2 + ktl;
      short8v ah = *(const short8v*)(wdp + ((kt*4 + mt2)*64 + l)*8);
      short8v al = *(const short8v*)(wdp + (((6 + kt)*4 + mt2)*64 + l)*8);
      #pragma unroll
      for (int ctl = 0; ctl < 7; ++ctl) {
        int rowb = th2*112 + ctl*16 + r;
        if (rowb > 199) rowb = 199;       // clamp: tw>=200 discarded anyway
        int bir = (ktl*64 + g*16) ^ ((rowb & 7) << 4);
        short8v b = *(const short8v*)(xab + rowb*128 + bir);
        acc2[ctl] = __builtin_amdgcn_mfma_f32_16x16x32_bf16(ah, b, acc2[ctl], 0,0,0);
        acc2[ctl] = __builtin_amdgcn_mfma_f32_16x16x32_bf16(al, b, acc2[ctl], 0,0,0);
      }
    }
    __syncthreads();   // protects xab rewrite (next s)
  }

  // epilogue: register-direct bias + bf16 z' store + BN1 stats (no LDS)
  {
    int o0 = mt2*16 + g*4;
    float bsum[4];
    #pragma unroll
    for (int reg = 0; reg < 4; ++reg) {
      int o = o0 + reg;
      bsum[reg] = bd[o] + bd[CB + o] + bd[2*CB + o];
    }
    float sm[4] = {0.f,0.f,0.f,0.f}, sq[4] = {0.f,0.f,0.f,0.f};
    unsigned short* zbase = zout + n*480000 + t0*1600 + o0;
    #pragma unroll
    for (int ctl = 0; ctl < 7; ++ctl) {
      int tw = th2*112 + ctl*16 + r;
      if (tw < lim) {
        ushort4 pk;
        float v0 = acc2[ctl][0] + bsum[0];
        float v1 = acc2[ctl][1] + bsum[1];
        float v2 = acc2[ctl][2] + bsum[2];
        float v3 = acc2[ctl][3] + bsum[3];
        pk.x = f2bf(v0); pk.y = f2bf(v1); pk.z = f2bf(v2); pk.w = f2bf(v3);
        *(ushort4*)(zbase + tw*64) = pk;
        sm[0] += v0; sm[1] += v1; sm[2] += v2; sm[3] += v3;
        sq[0] += v0*v0; sq[1] += v1*v1; sq[2] += v2*v2; sq[3] += v3*v3;
      }
    }
    // reduce across the 16 r-lanes (masks < 16 keep lanes within the g-group)
    #pragma unroll
    for (int m = 1; m < 16; m <<= 1) {
      #pragma unroll
      for (int reg = 0; reg < 4; ++reg) {
        sm[reg] += __shfl_xor(sm[reg], m);
        sq[reg] += __shfl_xor(sq[reg], m);
      }
    }
    if (r == 0) {
      #pragma unroll
      for (int reg = 0; reg < 4; ++reg) {
        atomicAdd(&wstat[WS_SUM1 + o0 + reg], sm[reg]);
        atomicAdd(&wstat[WS_SQ1  + o0 + reg], sq[reg]);
      }
    }
  }
}

// ---------------- K2/K4: fold BN stats into scale/shift ---------------------
__global__ void k_fin(const float* __restrict__ g, const float* __restrict__ b,
                      float* __restrict__ ws, int soff) {
  int c = threadIdx.x;
  float m   = ws[soff + c] * (1.f/NCNTF);
  float var = ws[soff + 64 + c] * (1.f/NCNTF) - m*m;
  float rstd = rsqrtf(var + 1e-5f);
  float sc = rstd * g[c];
  ws[soff + 128 + c] = sc;
  ws[soff + 192 + c] = b[c] - m * sc;
}

// ---------------- K3: MFMA 32x32x16 temporal conv, 512 thr / 8 waves --------
// tc stored [n][o][t*v] bf16 (coalesced rows; k5 streams it)
__global__ __launch_bounds__(512, 4) void k3_mfma(
    const unsigned short* __restrict__ zb, const unsigned short* __restrict__ xtb,
    const float* __restrict__ bt, const float* __restrict__ ws,
    float* __restrict__ wstat, unsigned short* __restrict__ tco)
{
  __shared__ __align__(16) char ubuf[52480];      // yT (51200) / tcl [64][205] f32
  __shared__ float s_sum[CB], s_sq[CB];
  int tid = threadIdx.x;
  int t0 = blockIdx.x * 8;                        // 38 blocks
  int n  = blockIdx.y;
  int wv = tid >> 6, l = tid & 63;
  int lane31 = l & 31, lh = l >> 5;
  int mt = wv & 1, cth = wv >> 1;                 // cth in 0..3, 2 col-tiles each

  if (tid < CB) { s_sum[tid] = 0.f; s_sq[tid] = 0.f; }

  // --- stage yT: 400 tv-rows x 64 i (bf16), swizzled, ushort4-vectorized ---
  {
    int c0 = (tid & 15) * 4;
    int rowsel = tid >> 4;                        // 0..31
    float4 sc4 = *(const float4*)(ws + WS_SC1 + c0);
    float4 sh4 = *(const float4*)(ws + WS_SH1 + c0);
    for (int it = 0; it < 13; ++it) {
      int tv = it*32 + rowsel;
      if (tv < 400) {
        int gt = t0 - 4 + tv/25;
        ushort4 yv = {0,0,0,0};
        if (gt >= 0 && gt < TB) {
          int addr = n*480000 + (t0-4)*1600 + tv*64 + c0;
          ushort4 z4 = *(const ushort4*)(zb + addr);
          ushort4 x4 = *(const ushort4*)(xtb + addr);
          yv.x = f2bf(fmaxf(fmaf(bf2f(z4.x), sc4.x, sh4.x) + bf2f(x4.x), 0.f));
          yv.y = f2bf(fmaxf(fmaf(bf2f(z4.y), sc4.y, sh4.y) + bf2f(x4.y), 0.f));
          yv.z = f2bf(fmaxf(fmaf(bf2f(z4.z), sc4.z, sh4.z) + bf2f(x4.z), 0.f));
          yv.w = f2bf(fmaxf(fmaf(bf2f(z4.w), sc4.w, sh4.w) + bf2f(x4.w), 0.f));
        }
        int wb = (tv << 7) + ((c0*2) ^ ((tv & 7) << 4));
        *(ushort4*)(ubuf + wb) = yv;
      }
    }
  }
  __syncthreads();

  // --- MFMA main loop: 36 K-tiles (two phases of 18), 2 col-tiles/wave ---
  const unsigned short* wtp = (const unsigned short*)((const char*)ws + WS_WTP_BYTE);
  f32x16 acc0, acc1;
  #pragma unroll
  for (int i = 0; i < 16; ++i) { acc0[i]=0.f; acc1[i]=0.f; }

  for (int ph = 0; ph < 2; ++ph) {
    short8v af[18];
    #pragma unroll
    for (int q = 0; q < 18; ++q)
      af[q] = *(const short8v*)(wtp + (((ph*18 + q)*2 + mt)*64 + l)*8);
    #pragma unroll
    for (int q = 0; q < 18; ++q) {
      int kt = ph*18 + q;
      int tap = kt >> 2;
      int ioff2 = ((kt & 3)*16 + lh*8) * 2;
#define DOCT(ACC, CTL) { \
      int col = (cth*2 + (CTL))*32 + lane31; \
      int tvB = (col < 200 ? col : 199) + 25*tap; \
      int ab = (tvB << 7) + (ioff2 ^ ((tvB & 7) << 4)); \
      short8v b = *(const short8v*)(ubuf + ab); \
      ACC = __builtin_amdgcn_mfma_f32_32x32x16_bf16(af[q], b, ACC, 0, 0, 0); }
      DOCT(acc0, 0) DOCT(acc1, 1)
#undef DOCT
    }
  }
  __syncthreads();

  // --- C-frags -> LDS tcl[o][205] f32 (stride 205: conflict-free) ---
  float* tcl = (float*)ubuf;
  {
    int rowbase = mt*32 + 4*lh;
#define STCT(ACC, CTL) { \
    int col = (cth*2 + (CTL))*32 + lane31; \
    if (col < 200) { \
      _Pragma("unroll") \
      for (int rg = 0; rg < 16; ++rg) { \
        int o = rowbase + (rg & 3) + 8*(rg >> 2); \
        tcl[o*205 + col] = ACC[rg]; } } }
    STCT(acc0, 0) STCT(acc1, 1)
#undef STCT
  }
  __syncthreads();

  int lim = 7500 - t0*25; if (lim > 200) lim = 200;
  // --- BN2 stats pass (8 chunks x 25) ---
  {
    int o = tid & 63, ch = tid >> 6;
    float bto = bt[o];
    float sm = 0.f, sq = 0.f;
    for (int q = 0; q < 25; ++q) {
      int tv = ch*25 + q;
      if (tv < lim) {
        float val = tcl[o*205 + tv] + bto;
        sm += val; sq += val*val;
      }
    }
    atomicAdd(&s_sum[o], sm);
    atomicAdd(&s_sq[o], sq);
  }
  // --- coalesced bf16 store: tc[n][o][t0*25 + tv] (8 o per wave) ---
  {
    for (int oo = 0; oo < 8; ++oo) {
      int o2 = wv*8 + oo;
      float bto2 = bt[o2];
      unsigned short* tr = tco + n*480000 + o2*7500 + t0*25;
      #pragma unroll
      for (int sub = 0; sub < 2; ++sub) {
        int tv2 = (sub*64 + l)*2;
        if (tv2 < lim) {
          ushort2 pk;
          pk.x = f2bf(tcl[o2*205 + tv2] + bto2);
          pk.y = f2bf(tcl[o2*205 + tv2 + 1] + bto2);
          *(ushort2*)(tr + tv2) = pk;
        }
      }
    }
  }
  __syncthreads();
  if (tid < CB) {
    atomicAdd(&wstat[WS_SUM2 + tid], s_sum[tid]);
    atomicAdd(&wstat[WS_SQ2  + tid], s_sq[tid]);
  }
}

// ---------------- K5: out = relu(bn2(tc) + x), pure streaming ---------------
__global__ __launch_bounds__(256) void k5_final(
    const float* __restrict__ x, const float* __restrict__ ws,
    const unsigned short* __restrict__ tc, float* __restrict__ out)
{
  int idx = blockIdx.x * blockDim.x + threadIdx.x;
  int stride = gridDim.x * blockDim.x;
  const int total4 = NB*CB*TB*VB/4;   // 1875 float4 per (n,c) plane
  for (int i = idx; i < total4; i += stride) {
    int c = (i / 1875) & 63;
    float sc = ws[WS_SC2 + c], sh = ws[WS_SH2 + c];
    ushort4 t4 = ((const ushort4*)tc)[i];
    float4  x4 = ((const float4*)x)[i];
    float4 r;
    r.x = fmaxf(fmaf(bf2f(t4.x), sc, sh) + x4.x, 0.f);
    r.y = fmaxf(fmaf(bf2f(t4.y), sc, sh) + x4.y, 0.f);
    r.z = fmaxf(fmaf(bf2f(t4.z), sc, sh) + x4.z, 0.f);
    r.w = fmaxf(fmaf(bf2f(t4.w), sc, sh) + x4.w, 0.f);
    ((float4*)out)[i] = r;
  }
}

extern "C" void kernel_launch(void* const* d_in, const int* in_sizes, int n_in,
                              void* d_out, int out_size, void* d_ws, size_t ws_size,
                              hipStream_t stream) {
  const float* x  = (const float*)d_in[0];
  const float* A  = (const float*)d_in[1];
  const float* PA = (const float*)d_in[2];
  const float* Wd = (const float*)d_in[3];
  const float* bd = (const float*)d_in[4];
  const float* g1 = (const float*)d_in[5];
  const float* b1 = (const float*)d_in[6];
  const float* Wt = (const float*)d_in[7];
  const float* bt = (const float*)d_in[8];
  const float* g2 = (const float*)d_in[9];
  const float* b2 = (const float*)d_in[10];

  float* ws = (float*)d_ws;
  unsigned short* zbuf = (unsigned short*)d_out;            // z' scratch
  unsigned short* xtb  = (unsigned short*)d_out + ZP_ELEMS; // xT scratch
  unsigned short* tc   = (unsigned short*)((char*)d_ws + WS_TC_BYTE);
  float* out = (float*)d_out;

  k0_prep<<<dim3(64), dim3(256), 0, stream>>>(A, PA, Wd, Wt, ws);
  k1_gcn<<<dim3(38, 64), dim3(512), 0, stream>>>(x, bd, ws, ws, zbuf, xtb);
  k_fin<<<dim3(1), dim3(64), 0, stream>>>(g1, b1, ws, 0);
  k3_mfma<<<dim3(38, 64), dim3(512), 0, stream>>>(zbuf, xtb, bt, ws, ws, tc);
  k_fin<<<dim3(1), dim3(64), 0, stream>>>(g2, b2, ws, 256);
  k5_final<<<dim3(2048), dim3(256), 0, stream>>>(x, ws, tc, out);
}

// Round 23
// 297.177 us; speedup vs baseline: 2.2308x; 2.2308x over previous
//
#include <hip/hip_runtime.h>

#define NB 64
#define CB 64
#define TB 300
#define VB 25
#define SB 3
#define KB 9
#define NCNTF 480000.0f  // N*T*V per channel

// ws float offsets (stats block)
#define WS_SUM1 0
#define WS_SQ1  64
#define WS_SC1  128
#define WS_SH1  192
#define WS_SUM2 256
#define WS_SQ2  320
#define WS_SC2  384
#define WS_SH2  448
// ws byte offsets
#define WS_WTP_BYTE 2048              // k3 A-frags (32x32): 36*2*64*8 bf16 = 73728 B
#define WS_AQP_BYTE 75776             // k1 stage1 A-frags (Aq hi/lo): 12*64*8 bf16
#define WS_WDP_BYTE 88064             // k1 stage2 A-frags (Wd hi/lo): 48*64*8 bf16
#define WS_TC_BYTE  262144            // tc bf16 [n][o][t*v]: 61.44 MB
// d_out scratch layout (ushort elements)
#define ZP_ELEMS    30720000          // z' bf16 [n][t][v][c] at d_out[0]
                                      // xT bf16 [n][t][v][c] at d_out[ZP_ELEMS]

typedef __attribute__((ext_vector_type(8))) short short8v;
typedef __attribute__((ext_vector_type(4))) float f32x4;
typedef __attribute__((ext_vector_type(16))) float f32x16;

__device__ __forceinline__ float bf2f(unsigned short u) {
  unsigned int v = ((unsigned int)u) << 16;
  float f; __builtin_memcpy(&f, &v, 4); return f;
}
__device__ __forceinline__ unsigned short f2bf(float f) {
  unsigned int x; __builtin_memcpy(&x, &f, 4);
  x += 0x7fffu + ((x >> 16) & 1u);
  return (unsigned short)(x >> 16);
}

// ---------------- K0: prep (pack Wt 32x32, Aq hi/lo, Wd hi/lo) --------------
__global__ void k0_prep(const float* __restrict__ A, const float* __restrict__ PA,
                        const float* __restrict__ Wd, const float* __restrict__ Wt,
                        float* __restrict__ ws) {
  int gid = blockIdx.x * 256 + threadIdx.x;
  int gs  = gridDim.x * 256;
  for (int i = gid; i < 512; i += gs) ws[i] = 0.f;
  // WtP32[kt][mt][l][j] = bf16(Wt[o=mt*32+(l&31)][i=(kt&3)*16+(l>>5)*8+j][tap=kt>>2])
  unsigned short* wtp = (unsigned short*)((char*)ws + WS_WTP_BYTE);
  for (int idx = gid; idx < 36*2*64*8; idx += gs) {
    int j = idx & 7, li = (idx >> 3) & 63, mt = (idx >> 9) & 1, kt = idx >> 10;
    int o = mt*32 + (li & 31);
    int i = (kt & 3)*16 + (li >> 5)*8 + j;
    int tap = kt >> 2;
    wtp[idx] = f2bf(Wt[(o*64 + i)*9 + tap]);
  }
  // AqP: frag f = s*4 + wt*2 + h; lane l; elem j: A[row=w][k=v] hi/lo split
  unsigned short* aqp = (unsigned short*)((char*)ws + WS_AQP_BYTE);
  for (int idx = gid; idx < 12*64*8; idx += gs) {
    int j = idx & 7, l = (idx >> 3) & 63, fi = idx >> 9;
    int h = fi & 1, wt = (fi >> 1) & 1, s = fi >> 2;
    int v = (l >> 4)*8 + j, w = wt*16 + (l & 15);
    unsigned short out = 0;
    if (v < VB && w < VB) {
      int ai = (s*VB + v)*VB + w;
      float a = A[ai] + PA[ai];
      float q = truncf(a * 1024.f);
      q = fminf(fmaxf(q, -32768.f), 32768.f);
      float aq = q * (1.f/1024.f);
      unsigned short hi = f2bf(aq);
      out = h ? f2bf(aq - bf2f(hi)) : hi;
    }
    aqp[idx] = out;
  }
  // WdP: frag fi = (h*6+kt)*4 + mt; A[row=o][k=s*64+c] hi/lo split
  unsigned short* wdp = (unsigned short*)((char*)ws + WS_WDP_BYTE);
  for (int idx = gid; idx < 48*64*8; idx += gs) {
    int j = idx & 7, l = (idx >> 3) & 63, fi = idx >> 9;
    int mt = fi & 3, q2 = fi >> 2;
    int kt = q2 % 6, h = q2 / 6;
    int k = kt*32 + (l >> 4)*8 + j;
    int s = k >> 6, c = k & 63, o = mt*16 + (l & 15);
    float wv = Wd[(s*64 + o)*64 + c];
    unsigned short hi = f2bf(wv);
    wdp[idx] = h ? f2bf(wv - bf2f(hi)) : hi;
  }
}

// ---------------- K1: MFMA GCN, 26.9KB LDS -> 4 blocks/CU, 2-pass epilogue --
__global__ __launch_bounds__(512, 4) void k1_gcn(
    const float* __restrict__ x, const float* __restrict__ bd,
    const float* __restrict__ ws, float* __restrict__ wstat,
    unsigned short* __restrict__ zout, unsigned short* __restrict__ xtout)
{
  __shared__ __align__(16) char k1lds[26400];
  __shared__ float s_sum[CB], s_sq[CB];
  unsigned short* xtl = (unsigned short*)k1lds;   // [200tv][66c] bf16 (phase A)
  char*  xab = k1lds;                             // xa_s [200][128B] swz (phase B)
  float* zgh = (float*)k1lds;                     // [100][65] f32 (phase C, 26000B)
  int tid = threadIdx.x;
  int t0 = blockIdx.x * 8;               // 38 blocks, t0 up to 296
  int n  = blockIdx.y;
  int wv = tid >> 6, l = tid & 63, r = l & 15, g = l >> 4;
  int lim = 7500 - t0*25; if (lim > 200) lim = 200;   // valid tv rows

  if (tid < CB) { s_sum[tid] = 0.f; s_sq[tid] = 0.f; }

  // stage: x float4 -> xtl transpose (bf16). Unstaged rows (tv>=lim) hold
  // garbage; they only feed output columns tw>=lim which are masked.
  for (int idx4 = tid; idx4 < 3200; idx4 += 512) {
    int c = idx4 / 50, q = idx4 - c*50;
    int tv0 = q*4;
    if (tv0 + 4 <= lim) {
      float4 xv = *(const float4*)(x + (size_t)(n*64 + c)*7500 + t0*25 + tv0);
      xtl[(tv0+0)*66 + c] = f2bf(xv.x);
      xtl[(tv0+1)*66 + c] = f2bf(xv.y);
      xtl[(tv0+2)*66 + c] = f2bf(xv.z);
      xtl[(tv0+3)*66 + c] = f2bf(xv.w);
    }
  }
  __syncthreads();

  // b1 fragments from xtl (wave wv owns t = wv); v>=25 -> 0
  short8v b1[4];
  #pragma unroll
  for (int ct = 0; ct < 4; ++ct) {
    int c = ct*16 + r;
    #pragma unroll
    for (int j = 0; j < 8; ++j) {
      int v = g*8 + j;
      b1[ct][j] = (v < VB) ? (short)xtl[(wv*25 + v)*66 + c] : (short)0;
    }
  }
  // xT emission (coalesced [tv][c] bf16 store)
  for (int idx = tid; idx < 12800; idx += 512) {
    int tv = idx >> 6, c = idx & 63;
    if (tv < lim)
      xtout[n*480000 + t0*1600 + idx] = xtl[tv*66 + c];
  }
  __syncthreads();   // xtl dead; xab takes over the same memory

  const unsigned short* aqp = (const unsigned short*)((const char*)ws + WS_AQP_BYTE);
  const unsigned short* wdp = (const unsigned short*)((const char*)ws + WS_WDP_BYTE);
  int mt2 = wv & 3, th2 = wv >> 2;
  f32x4 acc2[7];
  #pragma unroll
  for (int i = 0; i < 7; ++i) acc2[i] = (f32x4){0.f,0.f,0.f,0.f};

  for (int s = 0; s < SB; ++s) {
    // ---- stage1(s): xa_s[w][c] for all 8 t (wave wv = t); rows 0..199 ----
    #pragma unroll
    for (int wt = 0; wt < 2; ++wt) {
      short8v a1h = *(const short8v*)(aqp + ((s*4 + wt*2 + 0)*64 + l)*8);
      short8v a1l = *(const short8v*)(aqp + ((s*4 + wt*2 + 1)*64 + l)*8);
      f32x4 acc1[4];
      #pragma unroll
      for (int ct = 0; ct < 4; ++ct) acc1[ct] = (f32x4){0.f,0.f,0.f,0.f};
      #pragma unroll
      for (int ct = 0; ct < 4; ++ct) {
        acc1[ct] = __builtin_amdgcn_mfma_f32_16x16x32_bf16(a1h, b1[ct], acc1[ct], 0,0,0);
        acc1[ct] = __builtin_amdgcn_mfma_f32_16x16x32_bf16(a1l, b1[ct], acc1[ct], 0,0,0);
      }
      #pragma unroll
      for (int ct = 0; ct < 4; ++ct)
        #pragma unroll
        for (int reg = 0; reg < 4; ++reg) {
          int w = wt*16 + g*4 + reg;
          if (w < VB) {
            int row = wv*25 + w, c = ct*16 + r;
            int bir = (c*2) ^ ((row & 7) << 4);
            *(unsigned short*)(xab + row*128 + bir) = f2bf(acc1[ct][reg]);
          }
        }
    }
    __syncthreads();
    // ---- stage2(s): z += Wd[:,s-chunk] @ xa_s (K=64) ----
    #pragma unroll
    for (int ktl = 0; ktl < 2; ++ktl) {
      int kt = s*2 + ktl;
      short8v ah = *(const short8v*)(wdp + ((kt*4 + mt2)*64 + l)*8);
      short8v al = *(const short8v*)(wdp + (((6 + kt)*4 + mt2)*64 + l)*8);
      #pragma unroll
      for (int ctl = 0; ctl < 7; ++ctl) {
        int rowb = th2*112 + ctl*16 + r;
        if (rowb > 199) rowb = 199;       // clamp: tw>=200 discarded anyway
        int bir = (ktl*64 + g*16) ^ ((rowb & 7) << 4);
        short8v b = *(const short8v*)(xab + rowb*128 + bir);
        acc2[ctl] = __builtin_amdgcn_mfma_f32_16x16x32_bf16(ah, b, acc2[ctl], 0,0,0);
        acc2[ctl] = __builtin_amdgcn_mfma_f32_16x16x32_bf16(al, b, acc2[ctl], 0,0,0);
      }
    }
    __syncthreads();   // protects xab rewrite (next s) / zgh alias (last s)
  }

  // ---- 2-pass epilogue through zgh[100][65] (aliases xab, now dead) ----
  float bsum, smv = 0.f, sqv = 0.f;
  {
    int o = tid & 63;
    bsum = bd[o] + bd[CB + o] + bd[2*CB + o];
  }
  // pass A stage: th2==0 waves hold tw = ctl*16 + r (0..111); write tw<100
  if (th2 == 0) {
    #pragma unroll
    for (int ctl = 0; ctl < 7; ++ctl) {
      int tw = ctl*16 + r;
      if (tw < 100) {
        #pragma unroll
        for (int reg = 0; reg < 4; ++reg)
          zgh[tw*65 + mt2*16 + g*4 + reg] = acc2[ctl][reg];
      }
    }
  }
  __syncthreads();
  // pass A read: rows y=0..99 (tw = y)
  {
    int o = tid & 63, ch = tid >> 6;
    unsigned short* zr = zout + n*480000 + t0*1600 + o;
    for (int q = 0; q < 13; ++q) {
      int y = ch*13 + q;
      if (y < 100 && y < lim) {
        float val = zgh[y*65 + o] + bsum;
        zr[y*64] = f2bf(val);
        smv += val; sqv += val*val;
      }
    }
  }
  __syncthreads();
  // pass B stage: rows y = tw-100 for tw in [100,200)
  if (th2 == 0) {
    int tw = 6*16 + r;                  // 96..111
    if (tw >= 100) {
      #pragma unroll
      for (int reg = 0; reg < 4; ++reg)
        zgh[(tw-100)*65 + mt2*16 + g*4 + reg] = acc2[6][reg];
    }
  } else {
    #pragma unroll
    for (int ctl = 0; ctl < 6; ++ctl) {
      int tw = 112 + ctl*16 + r;        // 112..207
      if (tw < 200) {
        #pragma unroll
        for (int reg = 0; reg < 4; ++reg)
          zgh[(tw-100)*65 + mt2*16 + g*4 + reg] = acc2[ctl][reg];
      }
    }
  }
  __syncthreads();
  // pass B read: rows y=0..99 (tw = 100+y)
  {
    int o = tid & 63, ch = tid >> 6;
    unsigned short* zr = zout + n*480000 + t0*1600 + o;
    for (int q = 0; q < 13; ++q) {
      int y = ch*13 + q;
      int tw = 100 + y;
      if (y < 100 && tw < lim) {
        float val = zgh[tw*65 - 100*65 + o] + bsum;
        zr[tw*64] = f2bf(val);
        smv += val; sqv += val*val;
      }
    }
  }
  // stats: LDS reduce then one global burst (round-21 pattern)
  {
    int o = tid & 63;
    atomicAdd(&s_sum[o], smv);
    atomicAdd(&s_sq[o], sqv);
  }
  __syncthreads();
  if (tid < CB) {
    atomicAdd(&wstat[WS_SUM1 + tid], s_sum[tid]);
    atomicAdd(&wstat[WS_SQ1  + tid], s_sq[tid]);
  }
}

// ---------------- K2/K4: fold BN stats into scale/shift ---------------------
__global__ void k_fin(const float* __restrict__ g, const float* __restrict__ b,
                      float* __restrict__ ws, int soff) {
  int c = threadIdx.x;
  float m   = ws[soff + c] * (1.f/NCNTF);
  float var = ws[soff + 64 + c] * (1.f/NCNTF) - m*m;
  float rstd = rsqrtf(var + 1e-5f);
  float sc = rstd * g[c];
  ws[soff + 128 + c] = sc;
  ws[soff + 192 + c] = b[c] - m * sc;
}

// ---------------- K3: MFMA 32x32x16 temporal conv, 512 thr / 8 waves --------
// tc stored [n][o][t*v] bf16 (coalesced rows; k5 streams it)
__global__ __launch_bounds__(512, 4) void k3_mfma(
    const unsigned short* __restrict__ zb, const unsigned short* __restrict__ xtb,
    const float* __restrict__ bt, const float* __restrict__ ws,
    float* __restrict__ wstat, unsigned short* __restrict__ tco)
{
  __shared__ __align__(16) char ubuf[52480];      // yT (51200) / tcl [64][205] f32
  __shared__ float s_sum[CB], s_sq[CB];
  int tid = threadIdx.x;
  int t0 = blockIdx.x * 8;                        // 38 blocks
  int n  = blockIdx.y;
  int wv = tid >> 6, l = tid & 63;
  int lane31 = l & 31, lh = l >> 5;
  int mt = wv & 1, cth = wv >> 1;                 // cth in 0..3, 2 col-tiles each

  if (tid < CB) { s_sum[tid] = 0.f; s_sq[tid] = 0.f; }

  // --- stage yT: 400 tv-rows x 64 i (bf16), swizzled, ushort4-vectorized ---
  {
    int c0 = (tid & 15) * 4;
    int rowsel = tid >> 4;                        // 0..31
    float4 sc4 = *(const float4*)(ws + WS_SC1 + c0);
    float4 sh4 = *(const float4*)(ws + WS_SH1 + c0);
    for (int it = 0; it < 13; ++it) {
      int tv = it*32 + rowsel;
      if (tv < 400) {
        int gt = t0 - 4 + tv/25;
        ushort4 yv = {0,0,0,0};
        if (gt >= 0 && gt < TB) {
          int addr = n*480000 + (t0-4)*1600 + tv*64 + c0;
          ushort4 z4 = *(const ushort4*)(zb + addr);
          ushort4 x4 = *(const ushort4*)(xtb + addr);
          yv.x = f2bf(fmaxf(fmaf(bf2f(z4.x), sc4.x, sh4.x) + bf2f(x4.x), 0.f));
          yv.y = f2bf(fmaxf(fmaf(bf2f(z4.y), sc4.y, sh4.y) + bf2f(x4.y), 0.f));
          yv.z = f2bf(fmaxf(fmaf(bf2f(z4.z), sc4.z, sh4.z) + bf2f(x4.z), 0.f));
          yv.w = f2bf(fmaxf(fmaf(bf2f(z4.w), sc4.w, sh4.w) + bf2f(x4.w), 0.f));
        }
        int wb = (tv << 7) + ((c0*2) ^ ((tv & 7) << 4));
        *(ushort4*)(ubuf + wb) = yv;
      }
    }
  }
  __syncthreads();

  // --- MFMA main loop: 36 K-tiles (two phases of 18), 2 col-tiles/wave ---
  const unsigned short* wtp = (const unsigned short*)((const char*)ws + WS_WTP_BYTE);
  f32x16 acc0, acc1;
  #pragma unroll
  for (int i = 0; i < 16; ++i) { acc0[i]=0.f; acc1[i]=0.f; }

  for (int ph = 0; ph < 2; ++ph) {
    short8v af[18];
    #pragma unroll
    for (int q = 0; q < 18; ++q)
      af[q] = *(const short8v*)(wtp + (((ph*18 + q)*2 + mt)*64 + l)*8);
    #pragma unroll
    for (int q = 0; q < 18; ++q) {
      int kt = ph*18 + q;
      int tap = kt >> 2;
      int ioff2 = ((kt & 3)*16 + lh*8) * 2;
#define DOCT(ACC, CTL) { \
      int col = (cth*2 + (CTL))*32 + lane31; \
      int tvB = (col < 200 ? col : 199) + 25*tap; \
      int ab = (tvB << 7) + (ioff2 ^ ((tvB & 7) << 4)); \
      short8v b = *(const short8v*)(ubuf + ab); \
      ACC = __builtin_amdgcn_mfma_f32_32x32x16_bf16(af[q], b, ACC, 0, 0, 0); }
      DOCT(acc0, 0) DOCT(acc1, 1)
#undef DOCT
    }
  }
  __syncthreads();

  // --- C-frags -> LDS tcl[o][205] f32 (stride 205: conflict-free) ---
  float* tcl = (float*)ubuf;
  {
    int rowbase = mt*32 + 4*lh;
#define STCT(ACC, CTL) { \
    int col = (cth*2 + (CTL))*32 + lane31; \
    if (col < 200) { \
      _Pragma("unroll") \
      for (int rg = 0; rg < 16; ++rg) { \
        int o = rowbase + (rg & 3) + 8*(rg >> 2); \
        tcl[o*205 + col] = ACC[rg]; } } }
    STCT(acc0, 0) STCT(acc1, 1)
#undef STCT
  }
  __syncthreads();

  int lim = 7500 - t0*25; if (lim > 200) lim = 200;
  // --- BN2 stats pass (8 chunks x 25) ---
  {
    int o = tid & 63, ch = tid >> 6;
    float bto = bt[o];
    float sm = 0.f, sq = 0.f;
    for (int q = 0; q < 25; ++q) {
      int tv = ch*25 + q;
      if (tv < lim) {
        float val = tcl[o*205 + tv] + bto;
        sm += val; sq += val*val;
      }
    }
    atomicAdd(&s_sum[o], sm);
    atomicAdd(&s_sq[o], sq);
  }
  // --- coalesced bf16 store: tc[n][o][t0*25 + tv] (8 o per wave) ---
  {
    for (int oo = 0; oo < 8; ++oo) {
      int o2 = wv*8 + oo;
      float bto2 = bt[o2];
      unsigned short* tr = tco + n*480000 + o2*7500 + t0*25;
      #pragma unroll
      for (int sub = 0; sub < 2; ++sub) {
        int tv2 = (sub*64 + l)*2;
        if (tv2 < lim) {
          ushort2 pk;
          pk.x = f2bf(tcl[o2*205 + tv2] + bto2);
          pk.y = f2bf(tcl[o2*205 + tv2 + 1] + bto2);
          *(ushort2*)(tr + tv2) = pk;
        }
      }
    }
  }
  __syncthreads();
  if (tid < CB) {
    atomicAdd(&wstat[WS_SUM2 + tid], s_sum[tid]);
    atomicAdd(&wstat[WS_SQ2  + tid], s_sq[tid]);
  }
}

// ---------------- K5: out = relu(bn2(tc) + x), pure streaming ---------------
__global__ __launch_bounds__(256) void k5_final(
    const float* __restrict__ x, const float* __restrict__ ws,
    const unsigned short* __restrict__ tc, float* __restrict__ out)
{
  int idx = blockIdx.x * blockDim.x + threadIdx.x;
  int stride = gridDim.x * blockDim.x;
  const int total4 = NB*CB*TB*VB/4;   // 1875 float4 per (n,c) plane
  for (int i = idx; i < total4; i += stride) {
    int c = (i / 1875) & 63;
    float sc = ws[WS_SC2 + c], sh = ws[WS_SH2 + c];
    ushort4 t4 = ((const ushort4*)tc)[i];
    float4  x4 = ((const float4*)x)[i];
    float4 r;
    r.x = fmaxf(fmaf(bf2f(t4.x), sc, sh) + x4.x, 0.f);
    r.y = fmaxf(fmaf(bf2f(t4.y), sc, sh) + x4.y, 0.f);
    r.z = fmaxf(fmaf(bf2f(t4.z), sc, sh) + x4.z, 0.f);
    r.w = fmaxf(fmaf(bf2f(t4.w), sc, sh) + x4.w, 0.f);
    ((float4*)out)[i] = r;
  }
}

extern "C" void kernel_launch(void* const* d_in, const int* in_sizes, int n_in,
                              void* d_out, int out_size, void* d_ws, size_t ws_size,
                              hipStream_t stream) {
  const float* x  = (const float*)d_in[0];
  const float* A  = (const float*)d_in[1];
  const float* PA = (const float*)d_in[2];
  const float* Wd = (const float*)d_in[3];
  const float* bd = (const float*)d_in[4];
  const float* g1 = (const float*)d_in[5];
  const float* b1 = (const float*)d_in[6];
  const float* Wt = (const float*)d_in[7];
  const float* bt = (const float*)d_in[8];
  const float* g2 = (const float*)d_in[9];
  const float* b2 = (const float*)d_in[10];

  float* ws = (float*)d_ws;
  unsigned short* zbuf = (unsigned short*)d_out;            // z' scratch
  unsigned short* xtb  = (unsigned short*)d_out + ZP_ELEMS; // xT scratch
  unsigned short* tc   = (unsigned short*)((char*)d_ws + WS_TC_BYTE);
  float* out = (float*)d_out;

  k0_prep<<<dim3(64), dim3(256), 0, stream>>>(A, PA, Wd, Wt, ws);
  k1_gcn<<<dim3(38, 64), dim3(512), 0, stream>>>(x, bd, ws, ws, zbuf, xtb);
  k_fin<<<dim3(1), dim3(64), 0, stream>>>(g1, b1, ws, 0);
  k3_mfma<<<dim3(38, 64), dim3(512), 0, stream>>>(zbuf, xtb, bt, ws, ws, tc);
  k_fin<<<dim3(1), dim3(64), 0, stream>>>(g2, b2, ws, 256);
  k5_final<<<dim3(2048), dim3(256), 0, stream>>>(x, ws, tc, out);
}

// Round 24
// 292.589 us; speedup vs baseline: 2.2658x; 1.0157x over previous
//
#include <hip/hip_runtime.h>

#define NB 64
#define CB 64
#define TB 300
#define VB 25
#define SB 3
#define KB 9
#define NCNTF 480000.0f  // N*T*V per channel

// ws float offsets (stats block)
#define WS_SUM1 0
#define WS_SQ1  64
#define WS_SC1  128
#define WS_SH1  192
#define WS_SUM2 256
#define WS_SQ2  320
#define WS_SC2  384
#define WS_SH2  448
// ws byte offsets
#define WS_WTP_BYTE 2048              // k3 A-frags (32x32): 36*2*64*8 bf16 = 73728 B
#define WS_AQP_BYTE 75776             // k1 stage1 A-frags (Aq hi/lo): 12*64*8 bf16
#define WS_WDP_BYTE 88064             // k1 stage2 A-frags (Wd hi/lo): 48*64*8 bf16
#define WS_TC_BYTE  262144            // tc bf16 [n][o][t*v]: 61.44 MB
// d_out scratch layout (ushort elements)
#define ZP_ELEMS    30720000          // z' bf16 [n][t][v][c] at d_out[0]
                                      // xT bf16 [n][t][v][c] at d_out[ZP_ELEMS]

typedef __attribute__((ext_vector_type(8))) short short8v;
typedef __attribute__((ext_vector_type(4))) float f32x4;
typedef __attribute__((ext_vector_type(16))) float f32x16;

__device__ __forceinline__ float bf2f(unsigned short u) {
  unsigned int v = ((unsigned int)u) << 16;
  float f; __builtin_memcpy(&f, &v, 4); return f;
}
__device__ __forceinline__ unsigned short f2bf(float f) {
  unsigned int x; __builtin_memcpy(&x, &f, 4);
  x += 0x7fffu + ((x >> 16) & 1u);
  return (unsigned short)(x >> 16);
}

// ---------------- K0: prep (pack Wt 32x32, Aq hi/lo, Wd hi/lo) --------------
__global__ void k0_prep(const float* __restrict__ A, const float* __restrict__ PA,
                        const float* __restrict__ Wd, const float* __restrict__ Wt,
                        float* __restrict__ ws) {
  int gid = blockIdx.x * 256 + threadIdx.x;
  int gs  = gridDim.x * 256;
  for (int i = gid; i < 512; i += gs) ws[i] = 0.f;
  // WtP32[kt][mt][l][j] = bf16(Wt[o=mt*32+(l&31)][i=(kt&3)*16+(l>>5)*8+j][tap=kt>>2])
  unsigned short* wtp = (unsigned short*)((char*)ws + WS_WTP_BYTE);
  for (int idx = gid; idx < 36*2*64*8; idx += gs) {
    int j = idx & 7, li = (idx >> 3) & 63, mt = (idx >> 9) & 1, kt = idx >> 10;
    int o = mt*32 + (li & 31);
    int i = (kt & 3)*16 + (li >> 5)*8 + j;
    int tap = kt >> 2;
    wtp[idx] = f2bf(Wt[(o*64 + i)*9 + tap]);
  }
  // AqP: frag f = s*4 + wt*2 + h; lane l; elem j: A[row=w][k=v] hi/lo split
  unsigned short* aqp = (unsigned short*)((char*)ws + WS_AQP_BYTE);
  for (int idx = gid; idx < 12*64*8; idx += gs) {
    int j = idx & 7, l = (idx >> 3) & 63, fi = idx >> 9;
    int h = fi & 1, wt = (fi >> 1) & 1, s = fi >> 2;
    int v = (l >> 4)*8 + j, w = wt*16 + (l & 15);
    unsigned short out = 0;
    if (v < VB && w < VB) {
      int ai = (s*VB + v)*VB + w;
      float a = A[ai] + PA[ai];
      float q = truncf(a * 1024.f);
      q = fminf(fmaxf(q, -32768.f), 32768.f);
      float aq = q * (1.f/1024.f);
      unsigned short hi = f2bf(aq);
      out = h ? f2bf(aq - bf2f(hi)) : hi;
    }
    aqp[idx] = out;
  }
  // WdP: frag fi = (h*6+kt)*4 + mt; A[row=o][k=s*64+c] hi/lo split
  unsigned short* wdp = (unsigned short*)((char*)ws + WS_WDP_BYTE);
  for (int idx = gid; idx < 48*64*8; idx += gs) {
    int j = idx & 7, l = (idx >> 3) & 63, fi = idx >> 9;
    int mt = fi & 3, q2 = fi >> 2;
    int kt = q2 % 6, h = q2 / 6;
    int k = kt*32 + (l >> 4)*8 + j;
    int s = k >> 6, c = k & 63, o = mt*16 + (l & 15);
    float wv = Wd[(s*64 + o)*64 + c];
    unsigned short hi = f2bf(wv);
    wdp[idx] = h ? f2bf(wv - bf2f(hi)) : hi;
  }
}

// ---------------- K1: MFMA GCN, 8-t tiles, 51KB LDS, 3 blocks/CU, no spill --
__global__ __launch_bounds__(512, 4) void k1_gcn(
    const float* __restrict__ x, const float* __restrict__ bd,
    const float* __restrict__ ws, float* __restrict__ wstat,
    unsigned short* __restrict__ zout, unsigned short* __restrict__ xtout)
{
  __shared__ __align__(16) char k1lds[52000];
  __shared__ float s_sum[CB], s_sq[CB];
  unsigned short* xtl = (unsigned short*)k1lds;            // [200tv][66c] bf16 26400B
  char*  xab = k1lds + 26400;                              // xa_s [200 rows][128B] swz
  float* zg  = (float*)k1lds;                              // [200tw][65o] f32 (alias)
  int tid = threadIdx.x;
  int t0 = blockIdx.x * 8;               // 38 blocks, t0 up to 296
  int n  = blockIdx.y;
  int wv = tid >> 6, l = tid & 63, r = l & 15, g = l >> 4;
  int lim = 7500 - t0*25; if (lim > 200) lim = 200;   // valid tv rows

  if (tid < CB) { s_sum[tid] = 0.f; s_sq[tid] = 0.f; }

  // stage: x float4 -> xtl transpose (bf16). Unstaged rows (tv>=lim) hold
  // garbage; they only feed output columns tw>=lim which are masked (GEMM
  // columns are independent).
  for (int idx4 = tid; idx4 < 3200; idx4 += 512) {
    int c = idx4 / 50, q = idx4 - c*50;
    int tv0 = q*4;
    if (tv0 + 4 <= lim) {
      float4 xv = *(const float4*)(x + (size_t)(n*64 + c)*7500 + t0*25 + tv0);
      xtl[(tv0+0)*66 + c] = f2bf(xv.x);
      xtl[(tv0+1)*66 + c] = f2bf(xv.y);
      xtl[(tv0+2)*66 + c] = f2bf(xv.z);
      xtl[(tv0+3)*66 + c] = f2bf(xv.w);
    }
  }
  __syncthreads();

  // b1 fragments from xtl (wave wv owns t = wv); v>=25 -> 0
  short8v b1[4];
  #pragma unroll
  for (int ct = 0; ct < 4; ++ct) {
    int c = ct*16 + r;
    #pragma unroll
    for (int j = 0; j < 8; ++j) {
      int v = g*8 + j;
      b1[ct][j] = (v < VB) ? (short)xtl[(wv*25 + v)*66 + c] : (short)0;
    }
  }
  // xT emission (coalesced [tv][c] bf16 store); no barrier needed after:
  // stage1 below writes xab only, xtl is not written again.
  for (int idx = tid; idx < 12800; idx += 512) {
    int tv = idx >> 6, c = idx & 63;
    if (tv < lim)
      xtout[n*480000 + t0*1600 + idx] = xtl[tv*66 + c];
  }

  const unsigned short* aqp = (const unsigned short*)((const char*)ws + WS_AQP_BYTE);
  const unsigned short* wdp = (const unsigned short*)((const char*)ws + WS_WDP_BYTE);
  int mt2 = wv & 3, th2 = wv >> 2;
  f32x4 acc2[7];
  #pragma unroll
  for (int i = 0; i < 7; ++i) acc2[i] = (f32x4){0.f,0.f,0.f,0.f};

  for (int s = 0; s < SB; ++s) {
    // ---- stage1(s): xa_s[w][c] for all 8 t (wave wv = t); rows 0..199 ----
    #pragma unroll
    for (int wt = 0; wt < 2; ++wt) {
      short8v a1h = *(const short8v*)(aqp + ((s*4 + wt*2 + 0)*64 + l)*8);
      short8v a1l = *(const short8v*)(aqp + ((s*4 + wt*2 + 1)*64 + l)*8);
      f32x4 acc1[4];
      #pragma unroll
      for (int ct = 0; ct < 4; ++ct) acc1[ct] = (f32x4){0.f,0.f,0.f,0.f};
      #pragma unroll
      for (int ct = 0; ct < 4; ++ct) {
        acc1[ct] = __builtin_amdgcn_mfma_f32_16x16x32_bf16(a1h, b1[ct], acc1[ct], 0,0,0);
        acc1[ct] = __builtin_amdgcn_mfma_f32_16x16x32_bf16(a1l, b1[ct], acc1[ct], 0,0,0);
      }
      #pragma unroll
      for (int ct = 0; ct < 4; ++ct)
        #pragma unroll
        for (int reg = 0; reg < 4; ++reg) {
          int w = wt*16 + g*4 + reg;
          if (w < VB) {
            int row = wv*25 + w, c = ct*16 + r;
            int bir = (c*2) ^ ((row & 7) << 4);
            *(unsigned short*)(xab + row*128 + bir) = f2bf(acc1[ct][reg]);
          }
        }
    }
    __syncthreads();
    // ---- stage2(s): z += Wd[:,s-chunk] @ xa_s (K=64) ----
    #pragma unroll
    for (int ktl = 0; ktl < 2; ++ktl) {
      int kt = s*2 + ktl;
      short8v ah = *(const short8v*)(wdp + ((kt*4 + mt2)*64 + l)*8);
      short8v al = *(const short8v*)(wdp + (((6 + kt)*4 + mt2)*64 + l)*8);
      #pragma unroll
      for (int ctl = 0; ctl < 7; ++ctl) {
        int rowb = th2*112 + ctl*16 + r;
        if (rowb > 199) rowb = 199;       // clamp: tw>=200 discarded anyway
        int bir = (ktl*64 + g*16) ^ ((rowb & 7) << 4);
        short8v b = *(const short8v*)(xab + rowb*128 + bir);
        acc2[ctl] = __builtin_amdgcn_mfma_f32_16x16x32_bf16(ah, b, acc2[ctl], 0,0,0);
        acc2[ctl] = __builtin_amdgcn_mfma_f32_16x16x32_bf16(al, b, acc2[ctl], 0,0,0);
      }
    }
    __syncthreads();   // protects xab rewrite (next s) / zg alias (last s)
  }

  // zg write (aliases xtl+xab; all reads completed at last sync)
  #pragma unroll
  for (int ctl = 0; ctl < 7; ++ctl) {
    int tw = th2*112 + ctl*16 + r;
    if (tw < 200) {
      #pragma unroll
      for (int reg = 0; reg < 4; ++reg)
        zg[tw*65 + mt2*16 + g*4 + reg] = acc2[ctl][reg];
    }
  }
  __syncthreads();

  // epilogue: bias + BN1 stats + coalesced bf16 z' store ([n][t][v][c])
  {
    int o = tid & 63, chunk = tid >> 6;
    float bsum = bd[o] + bd[CB + o] + bd[2*CB + o];
    unsigned short* zr = zout + n*480000 + t0*1600 + o;
    float sm = 0.f, sq = 0.f;
    for (int qq = 0; qq < 25; ++qq) {
      int tw = chunk*25 + qq;
      if (tw < lim) {
        float val = zg[tw*65 + o] + bsum;
        zr[tw*64] = f2bf(val);
        sm += val; sq += val*val;
      }
    }
    atomicAdd(&s_sum[o], sm);
    atomicAdd(&s_sq[o], sq);
  }
  __syncthreads();
  if (tid < CB) {
    atomicAdd(&wstat[WS_SUM1 + tid], s_sum[tid]);
    atomicAdd(&wstat[WS_SQ1  + tid], s_sq[tid]);
  }
}

// ---------------- K2/K4: fold BN stats into scale/shift ---------------------
__global__ void k_fin(const float* __restrict__ g, const float* __restrict__ b,
                      float* __restrict__ ws, int soff) {
  int c = threadIdx.x;
  float m   = ws[soff + c] * (1.f/NCNTF);
  float var = ws[soff + 64 + c] * (1.f/NCNTF) - m*m;
  float rstd = rsqrtf(var + 1e-5f);
  float sc = rstd * g[c];
  ws[soff + 128 + c] = sc;
  ws[soff + 192 + c] = b[c] - m * sc;
}

// ---------------- K3: MFMA 32x32x16 temporal conv, 512 thr / 8 waves --------
// tc stored [n][o][t*v] bf16 (coalesced rows; k5 streams it)
__global__ __launch_bounds__(512, 4) void k3_mfma(
    const unsigned short* __restrict__ zb, const unsigned short* __restrict__ xtb,
    const float* __restrict__ bt, const float* __restrict__ ws,
    float* __restrict__ wstat, unsigned short* __restrict__ tco)
{
  __shared__ __align__(16) char ubuf[52480];      // yT (51200) / tcl [64][205] f32
  __shared__ float s_sum[CB], s_sq[CB];
  int tid = threadIdx.x;
  int t0 = blockIdx.x * 8;                        // 38 blocks
  int n  = blockIdx.y;
  int wv = tid >> 6, l = tid & 63;
  int lane31 = l & 31, lh = l >> 5;
  int mt = wv & 1, cth = wv >> 1;                 // cth in 0..3, 2 col-tiles each

  if (tid < CB) { s_sum[tid] = 0.f; s_sq[tid] = 0.f; }

  // --- stage yT: 400 tv-rows x 64 i (bf16), swizzled, ushort4-vectorized ---
  {
    int c0 = (tid & 15) * 4;
    int rowsel = tid >> 4;                        // 0..31
    float4 sc4 = *(const float4*)(ws + WS_SC1 + c0);
    float4 sh4 = *(const float4*)(ws + WS_SH1 + c0);
    for (int it = 0; it < 13; ++it) {
      int tv = it*32 + rowsel;
      if (tv < 400) {
        int gt = t0 - 4 + tv/25;
        ushort4 yv = {0,0,0,0};
        if (gt >= 0 && gt < TB) {
          int addr = n*480000 + (t0-4)*1600 + tv*64 + c0;
          ushort4 z4 = *(const ushort4*)(zb + addr);
          ushort4 x4 = *(const ushort4*)(xtb + addr);
          yv.x = f2bf(fmaxf(fmaf(bf2f(z4.x), sc4.x, sh4.x) + bf2f(x4.x), 0.f));
          yv.y = f2bf(fmaxf(fmaf(bf2f(z4.y), sc4.y, sh4.y) + bf2f(x4.y), 0.f));
          yv.z = f2bf(fmaxf(fmaf(bf2f(z4.z), sc4.z, sh4.z) + bf2f(x4.z), 0.f));
          yv.w = f2bf(fmaxf(fmaf(bf2f(z4.w), sc4.w, sh4.w) + bf2f(x4.w), 0.f));
        }
        int wb = (tv << 7) + ((c0*2) ^ ((tv & 7) << 4));
        *(ushort4*)(ubuf + wb) = yv;
      }
    }
  }
  __syncthreads();

  // --- MFMA main loop: 36 K-tiles (two phases of 18), 2 col-tiles/wave ---
  const unsigned short* wtp = (const unsigned short*)((const char*)ws + WS_WTP_BYTE);
  f32x16 acc0, acc1;
  #pragma unroll
  for (int i = 0; i < 16; ++i) { acc0[i]=0.f; acc1[i]=0.f; }

  for (int ph = 0; ph < 2; ++ph) {
    short8v af[18];
    #pragma unroll
    for (int q = 0; q < 18; ++q)
      af[q] = *(const short8v*)(wtp + (((ph*18 + q)*2 + mt)*64 + l)*8);
    #pragma unroll
    for (int q = 0; q < 18; ++q) {
      int kt = ph*18 + q;
      int tap = kt >> 2;
      int ioff2 = ((kt & 3)*16 + lh*8) * 2;
#define DOCT(ACC, CTL) { \
      int col = (cth*2 + (CTL))*32 + lane31; \
      int tvB = (col < 200 ? col : 199) + 25*tap; \
      int ab = (tvB << 7) + (ioff2 ^ ((tvB & 7) << 4)); \
      short8v b = *(const short8v*)(ubuf + ab); \
      ACC = __builtin_amdgcn_mfma_f32_32x32x16_bf16(af[q], b, ACC, 0, 0, 0); }
      DOCT(acc0, 0) DOCT(acc1, 1)
#undef DOCT
    }
  }
  __syncthreads();

  // --- C-frags -> LDS tcl[o][205] f32 (stride 205: conflict-free) ---
  float* tcl = (float*)ubuf;
  {
    int rowbase = mt*32 + 4*lh;
#define STCT(ACC, CTL) { \
    int col = (cth*2 + (CTL))*32 + lane31; \
    if (col < 200) { \
      _Pragma("unroll") \
      for (int rg = 0; rg < 16; ++rg) { \
        int o = rowbase + (rg & 3) + 8*(rg >> 2); \
        tcl[o*205 + col] = ACC[rg]; } } }
    STCT(acc0, 0) STCT(acc1, 1)
#undef STCT
  }
  __syncthreads();

  int lim = 7500 - t0*25; if (lim > 200) lim = 200;
  // --- BN2 stats pass (8 chunks x 25) ---
  {
    int o = tid & 63, ch = tid >> 6;
    float bto = bt[o];
    float sm = 0.f, sq = 0.f;
    for (int q = 0; q < 25; ++q) {
      int tv = ch*25 + q;
      if (tv < lim) {
        float val = tcl[o*205 + tv] + bto;
        sm += val; sq += val*val;
      }
    }
    atomicAdd(&s_sum[o], sm);
    atomicAdd(&s_sq[o], sq);
  }
  // --- coalesced bf16 store: tc[n][o][t0*25 + tv] (8 o per wave) ---
  {
    for (int oo = 0; oo < 8; ++oo) {
      int o2 = wv*8 + oo;
      float bto2 = bt[o2];
      unsigned short* tr = tco + n*480000 + o2*7500 + t0*25;
      #pragma unroll
      for (int sub = 0; sub < 2; ++sub) {
        int tv2 = (sub*64 + l)*2;
        if (tv2 < lim) {
          ushort2 pk;
          pk.x = f2bf(tcl[o2*205 + tv2] + bto2);
          pk.y = f2bf(tcl[o2*205 + tv2 + 1] + bto2);
          *(ushort2*)(tr + tv2) = pk;
        }
      }
    }
  }
  __syncthreads();
  if (tid < CB) {
    atomicAdd(&wstat[WS_SUM2 + tid], s_sum[tid]);
    atomicAdd(&wstat[WS_SQ2  + tid], s_sq[tid]);
  }
}

// ---------------- K5: out = relu(bn2(tc) + x), pure streaming ---------------
__global__ __launch_bounds__(256) void k5_final(
    const float* __restrict__ x, const float* __restrict__ ws,
    const unsigned short* __restrict__ tc, float* __restrict__ out)
{
  int idx = blockIdx.x * blockDim.x + threadIdx.x;
  int stride = gridDim.x * blockDim.x;
  const int total4 = NB*CB*TB*VB/4;   // 1875 float4 per (n,c) plane
  for (int i = idx; i < total4; i += stride) {
    int c = (i / 1875) & 63;
    float sc = ws[WS_SC2 + c], sh = ws[WS_SH2 + c];
    ushort4 t4 = ((const ushort4*)tc)[i];
    float4  x4 = ((const float4*)x)[i];
    float4 r;
    r.x = fmaxf(fmaf(bf2f(t4.x), sc, sh) + x4.x, 0.f);
    r.y = fmaxf(fmaf(bf2f(t4.y), sc, sh) + x4.y, 0.f);
    r.z = fmaxf(fmaf(bf2f(t4.z), sc, sh) + x4.z, 0.f);
    r.w = fmaxf(fmaf(bf2f(t4.w), sc, sh) + x4.w, 0.f);
    ((float4*)out)[i] = r;
  }
}

extern "C" void kernel_launch(void* const* d_in, const int* in_sizes, int n_in,
                              void* d_out, int out_size, void* d_ws, size_t ws_size,
                              hipStream_t stream) {
  const float* x  = (const float*)d_in[0];
  const float* A  = (const float*)d_in[1];
  const float* PA = (const float*)d_in[2];
  const float* Wd = (const float*)d_in[3];
  const float* bd = (const float*)d_in[4];
  const float* g1 = (const float*)d_in[5];
  const float* b1 = (const float*)d_in[6];
  const float* Wt = (const float*)d_in[7];
  const float* bt = (const float*)d_in[8];
  const float* g2 = (const float*)d_in[9];
  const float* b2 = (const float*)d_in[10];

  float* ws = (float*)d_ws;
  unsigned short* zbuf = (unsigned short*)d_out;            // z' scratch
  unsigned short* xtb  = (unsigned short*)d_out + ZP_ELEMS; // xT scratch
  unsigned short* tc   = (unsigned short*)((char*)d_ws + WS_TC_BYTE);
  float* out = (float*)d_out;

  k0_prep<<<dim3(64), dim3(256), 0, stream>>>(A, PA, Wd, Wt, ws);
  k1_gcn<<<dim3(38, 64), dim3(512), 0, stream>>>(x, bd, ws, ws, zbuf, xtb);
  k_fin<<<dim3(1), dim3(64), 0, stream>>>(g1, b1, ws, 0);
  k3_mfma<<<dim3(38, 64), dim3(512), 0, stream>>>(zbuf, xtb, bt, ws, ws, tc);
  k_fin<<<dim3(1), dim3(64), 0, stream>>>(g2, b2, ws, 256);
  k5_final<<<dim3(2048), dim3(256), 0, stream>>>(x, ws, tc, out);
}

// Round 25
// 286.015 us; speedup vs baseline: 2.3179x; 1.0230x over previous
//
#include <hip/hip_runtime.h>

#define NB 64
#define CB 64
#define TB 300
#define VB 25
#define SB 3
#define KB 9
#define NCNTF 480000.0f  // N*T*V per channel

// ws float offsets (stats block)
#define WS_SUM1 0
#define WS_SQ1  64
#define WS_SC1  128
#define WS_SH1  192
#define WS_SUM2 256
#define WS_SQ2  320
#define WS_SC2  384
#define WS_SH2  448
// ws byte offsets
#define WS_WTP_BYTE 2048              // k3 A-frags (32x32): 36*2*64*8 bf16 = 73728 B
#define WS_AQP_BYTE 75776             // k1 stage1 A-frags (Aq hi/lo): 12*64*8 bf16
#define WS_WDP_BYTE 88064             // k1 stage2 A-frags (Wd hi/lo): 48*64*8 bf16
#define WS_TC_BYTE  262144            // tc bf16 [n][o][t*v]: 61.44 MB
// d_out scratch layout (ushort elements)
#define ZP_ELEMS    30720000          // z' bf16 [n][t][v][c] at d_out[0]
                                      // xT bf16 [n][t][v][c] at d_out[ZP_ELEMS]

typedef __attribute__((ext_vector_type(8))) short short8v;
typedef __attribute__((ext_vector_type(4))) float f32x4;
typedef __attribute__((ext_vector_type(16))) float f32x16;

__device__ __forceinline__ float bf2f(unsigned short u) {
  unsigned int v = ((unsigned int)u) << 16;
  float f; __builtin_memcpy(&f, &v, 4); return f;
}
__device__ __forceinline__ unsigned short f2bf(float f) {
  unsigned int x; __builtin_memcpy(&x, &f, 4);
  x += 0x7fffu + ((x >> 16) & 1u);
  return (unsigned short)(x >> 16);
}

// ---------------- K0: prep (pack Wt 32x32, Aq hi/lo, Wd hi/lo) --------------
__global__ void k0_prep(const float* __restrict__ A, const float* __restrict__ PA,
                        const float* __restrict__ Wd, const float* __restrict__ Wt,
                        float* __restrict__ ws) {
  int gid = blockIdx.x * 256 + threadIdx.x;
  int gs  = gridDim.x * 256;
  for (int i = gid; i < 512; i += gs) ws[i] = 0.f;
  // WtP32[kt][mt][l][j] = bf16(Wt[o=mt*32+(l&31)][i=(kt&3)*16+(l>>5)*8+j][tap=kt>>2])
  unsigned short* wtp = (unsigned short*)((char*)ws + WS_WTP_BYTE);
  for (int idx = gid; idx < 36*2*64*8; idx += gs) {
    int j = idx & 7, li = (idx >> 3) & 63, mt = (idx >> 9) & 1, kt = idx >> 10;
    int o = mt*32 + (li & 31);
    int i = (kt & 3)*16 + (li >> 5)*8 + j;
    int tap = kt >> 2;
    wtp[idx] = f2bf(Wt[(o*64 + i)*9 + tap]);
  }
  // AqP: frag f = s*4 + wt*2 + h; lane l; elem j: A[row=w][k=v] hi/lo split
  unsigned short* aqp = (unsigned short*)((char*)ws + WS_AQP_BYTE);
  for (int idx = gid; idx < 12*64*8; idx += gs) {
    int j = idx & 7, l = (idx >> 3) & 63, fi = idx >> 9;
    int h = fi & 1, wt = (fi >> 1) & 1, s = fi >> 2;
    int v = (l >> 4)*8 + j, w = wt*16 + (l & 15);
    unsigned short out = 0;
    if (v < VB && w < VB) {
      int ai = (s*VB + v)*VB + w;
      float a = A[ai] + PA[ai];
      float q = truncf(a * 1024.f);
      q = fminf(fmaxf(q, -32768.f), 32768.f);
      float aq = q * (1.f/1024.f);
      unsigned short hi = f2bf(aq);
      out = h ? f2bf(aq - bf2f(hi)) : hi;
    }
    aqp[idx] = out;
  }
  // WdP: frag fi = (h*6+kt)*4 + mt; A[row=o][k=s*64+c] hi/lo split
  unsigned short* wdp = (unsigned short*)((char*)ws + WS_WDP_BYTE);
  for (int idx = gid; idx < 48*64*8; idx += gs) {
    int j = idx & 7, l = (idx >> 3) & 63, fi = idx >> 9;
    int mt = fi & 3, q2 = fi >> 2;
    int kt = q2 % 6, h = q2 / 6;
    int k = kt*32 + (l >> 4)*8 + j;
    int s = k >> 6, c = k & 63, o = mt*16 + (l & 15);
    float wv = Wd[(s*64 + o)*64 + c];
    unsigned short hi = f2bf(wv);
    wdp[idx] = h ? f2bf(wv - bf2f(hi)) : hi;
  }
}

// ---------------- K1: MFMA GCN, ping-pong xa buffers (merged phases) --------
__global__ __launch_bounds__(512, 4) void k1_gcn(
    const float* __restrict__ x, const float* __restrict__ bd,
    const float* __restrict__ ws, float* __restrict__ wstat,
    unsigned short* __restrict__ zout, unsigned short* __restrict__ xtout)
{
  __shared__ __align__(16) char k1lds[52000];
  __shared__ float s_sum[CB], s_sq[CB];
  unsigned short* xtl = (unsigned short*)k1lds;   // [200tv][66c] bf16 26400B (phase A)
  char* xa0 = k1lds;                              // [200][128B] swz (aliases xtl)
  char* xa1 = k1lds + 26400;                      // [200][128B] swz
  float* zg  = (float*)k1lds;                     // [200tw][65o] f32 (phase C alias)
  int tid = threadIdx.x;
  int t0 = blockIdx.x * 8;               // 38 blocks, t0 up to 296
  int n  = blockIdx.y;
  int wv = tid >> 6, l = tid & 63, r = l & 15, g = l >> 4;
  int lim = 7500 - t0*25; if (lim > 200) lim = 200;   // valid tv rows

  if (tid < CB) { s_sum[tid] = 0.f; s_sq[tid] = 0.f; }

  // stage: x float4 -> xtl transpose (bf16). Unstaged rows (tv>=lim) hold
  // garbage; they only feed output columns tw>=lim which are masked.
  for (int idx4 = tid; idx4 < 3200; idx4 += 512) {
    int c = idx4 / 50, q = idx4 - c*50;
    int tv0 = q*4;
    if (tv0 + 4 <= lim) {
      float4 xv = *(const float4*)(x + (size_t)(n*64 + c)*7500 + t0*25 + tv0);
      xtl[(tv0+0)*66 + c] = f2bf(xv.x);
      xtl[(tv0+1)*66 + c] = f2bf(xv.y);
      xtl[(tv0+2)*66 + c] = f2bf(xv.z);
      xtl[(tv0+3)*66 + c] = f2bf(xv.w);
    }
  }
  __syncthreads();

  // b1 fragments from xtl (wave wv owns t = wv); v>=25 -> 0
  short8v b1[4];
  #pragma unroll
  for (int ct = 0; ct < 4; ++ct) {
    int c = ct*16 + r;
    #pragma unroll
    for (int j = 0; j < 8; ++j) {
      int v = g*8 + j;
      b1[ct][j] = (v < VB) ? (short)xtl[(wv*25 + v)*66 + c] : (short)0;
    }
  }
  // xT emission (coalesced [tv][c] bf16 store)
  for (int idx = tid; idx < 12800; idx += 512) {
    int tv = idx >> 6, c = idx & 63;
    if (tv < lim)
      xtout[n*480000 + t0*1600 + idx] = xtl[tv*66 + c];
  }
  __syncthreads();   // xtl dead; xa0 aliases it from here

  const unsigned short* aqp = (const unsigned short*)((const char*)ws + WS_AQP_BYTE);
  const unsigned short* wdp = (const unsigned short*)((const char*)ws + WS_WDP_BYTE);
  int mt2 = wv & 3, th2 = wv >> 2;
  f32x4 acc2[7];
  #pragma unroll
  for (int i = 0; i < 7; ++i) acc2[i] = (f32x4){0.f,0.f,0.f,0.f};

  auto STAGE1 = [&](int s, char* dst) {
    #pragma unroll
    for (int wt = 0; wt < 2; ++wt) {
      short8v a1h = *(const short8v*)(aqp + ((s*4 + wt*2 + 0)*64 + l)*8);
      short8v a1l = *(const short8v*)(aqp + ((s*4 + wt*2 + 1)*64 + l)*8);
      f32x4 acc1[4];
      #pragma unroll
      for (int ct = 0; ct < 4; ++ct) acc1[ct] = (f32x4){0.f,0.f,0.f,0.f};
      #pragma unroll
      for (int ct = 0; ct < 4; ++ct) {
        acc1[ct] = __builtin_amdgcn_mfma_f32_16x16x32_bf16(a1h, b1[ct], acc1[ct], 0,0,0);
        acc1[ct] = __builtin_amdgcn_mfma_f32_16x16x32_bf16(a1l, b1[ct], acc1[ct], 0,0,0);
      }
      #pragma unroll
      for (int ct = 0; ct < 4; ++ct)
        #pragma unroll
        for (int reg = 0; reg < 4; ++reg) {
          int w = wt*16 + g*4 + reg;
          if (w < VB) {
            int row = wv*25 + w, c = ct*16 + r;
            int bir = (c*2) ^ ((row & 7) << 4);
            *(unsigned short*)(dst + row*128 + bir) = f2bf(acc1[ct][reg]);
          }
        }
    }
  };
  auto STAGE2 = [&](int s, const char* src) {
    #pragma unroll
    for (int ktl = 0; ktl < 2; ++ktl) {
      short8v ah = *(const short8v*)(wdp + (((s*2 + ktl)*4 + mt2)*64 + l)*8);
      short8v al = *(const short8v*)(wdp + (((6 + s*2 + ktl)*4 + mt2)*64 + l)*8);
      #pragma unroll
      for (int ctl = 0; ctl < 7; ++ctl) {
        int rowb = th2*112 + ctl*16 + r;
        if (rowb > 199) rowb = 199;       // clamp: tw>=200 discarded anyway
        int bir = (ktl*64 + g*16) ^ ((rowb & 7) << 4);
        short8v b = *(const short8v*)(src + rowb*128 + bir);
        acc2[ctl] = __builtin_amdgcn_mfma_f32_16x16x32_bf16(ah, b, acc2[ctl], 0,0,0);
        acc2[ctl] = __builtin_amdgcn_mfma_f32_16x16x32_bf16(al, b, acc2[ctl], 0,0,0);
      }
    }
  };

  // merged-phase pipeline: P0: s1(0) | P1: s1(1)+s2(0) | P2: s1(2)+s2(1) | P3: s2(2)
  STAGE1(0, xa0);
  __syncthreads();
  STAGE1(1, xa1);
  STAGE2(0, xa0);
  __syncthreads();
  STAGE1(2, xa0);
  STAGE2(1, xa1);
  __syncthreads();
  STAGE2(2, xa0);
  __syncthreads();   // xa buffers dead; zg aliases them

  // zg write
  #pragma unroll
  for (int ctl = 0; ctl < 7; ++ctl) {
    int tw = th2*112 + ctl*16 + r;
    if (tw < 200) {
      #pragma unroll
      for (int reg = 0; reg < 4; ++reg)
        zg[tw*65 + mt2*16 + g*4 + reg] = acc2[ctl][reg];
    }
  }
  __syncthreads();

  // epilogue: bias + BN1 stats + coalesced bf16 z' store ([n][t][v][c])
  {
    int o = tid & 63, chunk = tid >> 6;
    float bsum = bd[o] + bd[CB + o] + bd[2*CB + o];
    unsigned short* zr = zout + n*480000 + t0*1600 + o;
    float sm = 0.f, sq = 0.f;
    for (int qq = 0; qq < 25; ++qq) {
      int tw = chunk*25 + qq;
      if (tw < lim) {
        float val = zg[tw*65 + o] + bsum;
        zr[tw*64] = f2bf(val);
        sm += val; sq += val*val;
      }
    }
    atomicAdd(&s_sum[o], sm);
    atomicAdd(&s_sq[o], sq);
  }
  __syncthreads();
  if (tid < CB) {
    atomicAdd(&wstat[WS_SUM1 + tid], s_sum[tid]);
    atomicAdd(&wstat[WS_SQ1  + tid], s_sq[tid]);
  }
}

// ---------------- K2/K4: fold BN stats into scale/shift ---------------------
__global__ void k_fin(const float* __restrict__ g, const float* __restrict__ b,
                      float* __restrict__ ws, int soff) {
  int c = threadIdx.x;
  float m   = ws[soff + c] * (1.f/NCNTF);
  float var = ws[soff + 64 + c] * (1.f/NCNTF) - m*m;
  float rstd = rsqrtf(var + 1e-5f);
  float sc = rstd * g[c];
  ws[soff + 128 + c] = sc;
  ws[soff + 192 + c] = b[c] - m * sc;
}

// ---------------- K3: MFMA 32x32x16 temporal conv, 512 thr / 8 waves --------
// tc stored [n][o][t*v] bf16 (coalesced rows; k5 streams it)
__global__ __launch_bounds__(512, 4) void k3_mfma(
    const unsigned short* __restrict__ zb, const unsigned short* __restrict__ xtb,
    const float* __restrict__ bt, const float* __restrict__ ws,
    float* __restrict__ wstat, unsigned short* __restrict__ tco)
{
  __shared__ __align__(16) char ubuf[52480];      // yT (51200) / tcl [64][205] f32
  __shared__ float s_sum[CB], s_sq[CB];
  int tid = threadIdx.x;
  int t0 = blockIdx.x * 8;                        // 38 blocks
  int n  = blockIdx.y;
  int wv = tid >> 6, l = tid & 63;
  int lane31 = l & 31, lh = l >> 5;
  int mt = wv & 1, cth = wv >> 1;                 // cth in 0..3, 2 col-tiles each

  if (tid < CB) { s_sum[tid] = 0.f; s_sq[tid] = 0.f; }

  // --- stage yT: 400 tv-rows x 64 i (bf16), swizzled, ushort4-vectorized ---
  {
    int c0 = (tid & 15) * 4;
    int rowsel = tid >> 4;                        // 0..31
    float4 sc4 = *(const float4*)(ws + WS_SC1 + c0);
    float4 sh4 = *(const float4*)(ws + WS_SH1 + c0);
    for (int it = 0; it < 13; ++it) {
      int tv = it*32 + rowsel;
      if (tv < 400) {
        int gt = t0 - 4 + tv/25;
        ushort4 yv = {0,0,0,0};
        if (gt >= 0 && gt < TB) {
          int addr = n*480000 + (t0-4)*1600 + tv*64 + c0;
          ushort4 z4 = *(const ushort4*)(zb + addr);
          ushort4 x4 = *(const ushort4*)(xtb + addr);
          yv.x = f2bf(fmaxf(fmaf(bf2f(z4.x), sc4.x, sh4.x) + bf2f(x4.x), 0.f));
          yv.y = f2bf(fmaxf(fmaf(bf2f(z4.y), sc4.y, sh4.y) + bf2f(x4.y), 0.f));
          yv.z = f2bf(fmaxf(fmaf(bf2f(z4.z), sc4.z, sh4.z) + bf2f(x4.z), 0.f));
          yv.w = f2bf(fmaxf(fmaf(bf2f(z4.w), sc4.w, sh4.w) + bf2f(x4.w), 0.f));
        }
        int wb = (tv << 7) + ((c0*2) ^ ((tv & 7) << 4));
        *(ushort4*)(ubuf + wb) = yv;
      }
    }
  }
  __syncthreads();

  // --- MFMA main loop: 36 K-tiles (two phases of 18), 2 col-tiles/wave ---
  const unsigned short* wtp = (const unsigned short*)((const char*)ws + WS_WTP_BYTE);
  f32x16 acc0, acc1;
  #pragma unroll
  for (int i = 0; i < 16; ++i) { acc0[i]=0.f; acc1[i]=0.f; }

  for (int ph = 0; ph < 2; ++ph) {
    short8v af[18];
    #pragma unroll
    for (int q = 0; q < 18; ++q)
      af[q] = *(const short8v*)(wtp + (((ph*18 + q)*2 + mt)*64 + l)*8);
    #pragma unroll
    for (int q = 0; q < 18; ++q) {
      int kt = ph*18 + q;
      int tap = kt >> 2;
      int ioff2 = ((kt & 3)*16 + lh*8) * 2;
#define DOCT(ACC, CTL) { \
      int col = (cth*2 + (CTL))*32 + lane31; \
      int tvB = (col < 200 ? col : 199) + 25*tap; \
      int ab = (tvB << 7) + (ioff2 ^ ((tvB & 7) << 4)); \
      short8v b = *(const short8v*)(ubuf + ab); \
      ACC = __builtin_amdgcn_mfma_f32_32x32x16_bf16(af[q], b, ACC, 0, 0, 0); }
      DOCT(acc0, 0) DOCT(acc1, 1)
#undef DOCT
    }
  }
  __syncthreads();

  // --- C-frags -> LDS tcl[o][205] f32 (stride 205: conflict-free) ---
  float* tcl = (float*)ubuf;
  {
    int rowbase = mt*32 + 4*lh;
#define STCT(ACC, CTL) { \
    int col = (cth*2 + (CTL))*32 + lane31; \
    if (col < 200) { \
      _Pragma("unroll") \
      for (int rg = 0; rg < 16; ++rg) { \
        int o = rowbase + (rg & 3) + 8*(rg >> 2); \
        tcl[o*205 + col] = ACC[rg]; } } }
    STCT(acc0, 0) STCT(acc1, 1)
#undef STCT
  }
  __syncthreads();

  int lim = 7500 - t0*25; if (lim > 200) lim = 200;
  // --- BN2 stats pass (8 chunks x 25) ---
  {
    int o = tid & 63, ch = tid >> 6;
    float bto = bt[o];
    float sm = 0.f, sq = 0.f;
    for (int q = 0; q < 25; ++q) {
      int tv = ch*25 + q;
      if (tv < lim) {
        float val = tcl[o*205 + tv] + bto;
        sm += val; sq += val*val;
      }
    }
    atomicAdd(&s_sum[o], sm);
    atomicAdd(&s_sq[o], sq);
  }
  // --- coalesced bf16 store: tc[n][o][t0*25 + tv] (8 o per wave) ---
  {
    for (int oo = 0; oo < 8; ++oo) {
      int o2 = wv*8 + oo;
      float bto2 = bt[o2];
      unsigned short* tr = tco + n*480000 + o2*7500 + t0*25;
      #pragma unroll
      for (int sub = 0; sub < 2; ++sub) {
        int tv2 = (sub*64 + l)*2;
        if (tv2 < lim) {
          ushort2 pk;
          pk.x = f2bf(tcl[o2*205 + tv2] + bto2);
          pk.y = f2bf(tcl[o2*205 + tv2 + 1] + bto2);
          *(ushort2*)(tr + tv2) = pk;
        }
      }
    }
  }
  __syncthreads();
  if (tid < CB) {
    atomicAdd(&wstat[WS_SUM2 + tid], s_sum[tid]);
    atomicAdd(&wstat[WS_SQ2  + tid], s_sq[tid]);
  }
}

// ---------------- K5: out = relu(bn2(tc) + x), pure streaming ---------------
__global__ __launch_bounds__(256) void k5_final(
    const float* __restrict__ x, const float* __restrict__ ws,
    const unsigned short* __restrict__ tc, float* __restrict__ out)
{
  int idx = blockIdx.x * blockDim.x + threadIdx.x;
  int stride = gridDim.x * blockDim.x;
  const int total4 = NB*CB*TB*VB/4;   // 1875 float4 per (n,c) plane
  for (int i = idx; i < total4; i += stride) {
    int c = (i / 1875) & 63;
    float sc = ws[WS_SC2 + c], sh = ws[WS_SH2 + c];
    ushort4 t4 = ((const ushort4*)tc)[i];
    float4  x4 = ((const float4*)x)[i];
    float4 r;
    r.x = fmaxf(fmaf(bf2f(t4.x), sc, sh) + x4.x, 0.f);
    r.y = fmaxf(fmaf(bf2f(t4.y), sc, sh) + x4.y, 0.f);
    r.z = fmaxf(fmaf(bf2f(t4.z), sc, sh) + x4.z, 0.f);
    r.w = fmaxf(fmaf(bf2f(t4.w), sc, sh) + x4.w, 0.f);
    ((float4*)out)[i] = r;
  }
}

extern "C" void kernel_launch(void* const* d_in, const int* in_sizes, int n_in,
                              void* d_out, int out_size, void* d_ws, size_t ws_size,
                              hipStream_t stream) {
  const float* x  = (const float*)d_in[0];
  const float* A  = (const float*)d_in[1];
  const float* PA = (const float*)d_in[2];
  const float* Wd = (const float*)d_in[3];
  const float* bd = (const float*)d_in[4];
  const float* g1 = (const float*)d_in[5];
  const float* b1 = (const float*)d_in[6];
  const float* Wt = (const float*)d_in[7];
  const float* bt = (const float*)d_in[8];
  const float* g2 = (const float*)d_in[9];
  const float* b2 = (const float*)d_in[10];

  float* ws = (float*)d_ws;
  unsigned short* zbuf = (unsigned short*)d_out;            // z' scratch
  unsigned short* xtb  = (unsigned short*)d_out + ZP_ELEMS; // xT scratch
  unsigned short* tc   = (unsigned short*)((char*)d_ws + WS_TC_BYTE);
  float* out = (float*)d_out;

  k0_prep<<<dim3(64), dim3(256), 0, stream>>>(A, PA, Wd, Wt, ws);
  k1_gcn<<<dim3(38, 64), dim3(512), 0, stream>>>(x, bd, ws, ws, zbuf, xtb);
  k_fin<<<dim3(1), dim3(64), 0, stream>>>(g1, b1, ws, 0);
  k3_mfma<<<dim3(38, 64), dim3(512), 0, stream>>>(zbuf, xtb, bt, ws, ws, tc);
  k_fin<<<dim3(1), dim3(64), 0, stream>>>(g2, b2, ws, 256);
  k5_final<<<dim3(2048), dim3(256), 0, stream>>>(x, ws, tc, out);
}